// Round 2
// baseline (36338.382 us; speedup 1.0000x reference)
//
#include <hip/hip_runtime.h>
#include <hip/hip_cooperative_groups.h>

namespace cg = cooperative_groups;

#define T_STEPS 256
// sizes: M=4 N=48 H1=4160 HID=2320 3HID=6960 H2=768 OUT=192 KGIN=52

// workspace layout (float offsets)
#define WS_L1  0                  // 4160
#define WS_H0  4160               // 2320
#define WS_H1  6480               // 2320
#define WS_L2  8800               // 768
#define WS_V   9568               // 4*768
#define WS_C   12640              // 4
#define WS_XPO 12644              // 4 (fallback: x_post)
#define WS_XPR 12648              // 4 (fallback: x_prior)
#define WS_INN 12656              // 48 (fallback: innov)
#define WS_KG  12704              // 52 (fallback: kg_in)

__device__ __forceinline__ float wred(float v) {
#pragma unroll
  for (int m = 32; m; m >>= 1) v += __shfl_xor(v, m, 64);
  return v;
}
__device__ __forceinline__ float dot4(float4 a, float4 b) {
  return a.x * b.x + a.y * b.y + a.z * b.z + a.w * b.w;
}

// ======================= cooperative single-kernel path =======================
__global__ __launch_bounds__(256, 2) void knet(
    const float* __restrict__ y_seq, const float* __restrict__ x0,
    const float* __restrict__ h0, const float* __restrict__ A,
    const float* __restrict__ Cm, const float* __restrict__ W1,
    const float* __restrict__ b1, const float* __restrict__ W_ih,
    const float* __restrict__ W_hh, const float* __restrict__ b_ih,
    const float* __restrict__ b_hh, const float* __restrict__ W2,
    const float* __restrict__ b2, const float* __restrict__ W3,
    const float* __restrict__ b3, float* __restrict__ out,
    float* __restrict__ ws)
{
  cg::grid_group grid = cg::this_grid();
  const int tid    = threadIdx.x;
  const int lane   = tid & 63;
  const int wav    = tid >> 6;
  const int bid    = blockIdx.x;
  const int gt     = bid * 256 + tid;
  const int wave_g = bid * 4 + wav;
  const int NW     = gridDim.x * 4;

  __shared__ __align__(16) float4 s_buf4[1040];   // l1 staging (P2) / h_new staging (P3)
  __shared__ __align__(16) float4 s_h4[580];      // h_old staging (P2)
  __shared__ __align__(16) float s_kgin[52];
  __shared__ float s_innov[48];
  __shared__ float s_xpost[4], s_xprior[4], s_dx[4];
  __shared__ float s_sc2, s_sc4;

  for (int t = 0; t <= T_STEPS; ++t) {
    // ---------- P1a: x_post (= x_new of step t-1) ----------
    if (t == 0) {
      if (tid < 4) s_xpost[tid] = x0[tid];
    } else {
      const float4* vv  = (const float4*)(ws + WS_V + wav * 768);
      const float4* l2v = (const float4*)(ws + WS_L2);
      float acc = 0.f;
      for (int k = lane; k < 192; k += 64) acc += dot4(vv[k], l2v[k]);
      acc = wred(acc);
      if (lane == 0)
        s_xpost[wav] = s_xprior[wav] + (acc + ws[WS_C + wav]) * 1e-4f;
    }
    __syncthreads();
    if (bid == 0 && t > 0 && tid < 4) out[tid * T_STEPS + (t - 1)] = s_xpost[tid];
    if (t == T_STEPS) return;

    // ---------- P1b: x_prior, innov, kg_in ----------
    if (tid < 4) {
      float xp = 0.f;
#pragma unroll
      for (int j = 0; j < 4; j++) xp += A[tid * 4 + j] * s_xpost[j];
      s_xprior[tid] = xp;
    }
    __syncthreads();
    if (tid < 48) {
      float yp = Cm[tid * 5 + 4];
#pragma unroll
      for (int j = 0; j < 4; j++) yp += Cm[tid * 5 + j] * s_xprior[j];
      s_innov[tid] = y_seq[tid * T_STEPS + t] - yp;
    }
    if (tid >= 64 && tid < 68) {
      int i = tid - 64;
      s_dx[i] = s_xpost[i] - s_xprior[i];
    }
    __syncthreads();
    if (tid == 0) {
      float s2 = 0.f;
      for (int r = 0; r < 48; r++) s2 += s_innov[r] * s_innov[r];
      s_sc2 = 1.0f / fmaxf(sqrtf(s2), 1e-12f);
      float s4 = 0.f;
      for (int i = 0; i < 4; i++) s4 += s_dx[i] * s_dx[i];
      s_sc4 = 1.0f / fmaxf(sqrtf(s4), 1e-12f);
    }
    __syncthreads();
    if (tid < 48) s_kgin[tid] = s_innov[tid] * s_sc2;
    else if (tid < 52) s_kgin[tid] = s_dx[tid - 48] * s_sc4;
    __syncthreads();

    // ---------- P1c: l1 = relu(W1 @ kg_in + b1) ----------
    if (gt < 4160) {
      const float4* wr  = (const float4*)(W1 + (size_t)gt * 52);
      const float4* kg4 = (const float4*)s_kgin;
      float acc = b1[gt];
#pragma unroll
      for (int k = 0; k < 13; k++) acc += dot4(wr[k], kg4[k]);
      ws[WS_L1 + gt] = fmaxf(acc, 0.f);
    }
    grid.sync();  // S1: l1 complete

    // ---------- P2: gi + gh + gates -> h_new ----------
    {
      const float* h_old = (t == 0) ? h0 : (ws + (((t & 1) == 0) ? WS_H0 : WS_H1));
      float* h_new = ws + (((t & 1) == 0) ? WS_H1 : WS_H0);
      const float4* l1g = (const float4*)(ws + WS_L1);
      for (int i = tid; i < 1040; i += 256) s_buf4[i] = l1g[i];
      const float4* hog = (const float4*)h_old;
      for (int i = tid; i < 580; i += 256) s_h4[i] = hog[i];
      __syncthreads();
      const float* s_h = (const float*)s_h4;

      for (int j = wave_g; j < 2320; j += NW) {
        const float4* r0 = (const float4*)(W_ih + (size_t)j * 4160);
        const float4* r1 = (const float4*)(W_ih + (size_t)(j + 2320) * 4160);
        const float4* r2 = (const float4*)(W_ih + (size_t)(j + 4640) * 4160);
        float a0 = 0.f, a1 = 0.f, a2 = 0.f;
#pragma unroll 2
        for (int k = lane; k < 1040; k += 64) {
          float4 x = s_buf4[k];
          a0 += dot4(r0[k], x);
          a1 += dot4(r1[k], x);
          a2 += dot4(r2[k], x);
        }
        const float4* q0 = (const float4*)(W_hh + (size_t)j * 2320);
        const float4* q1 = (const float4*)(W_hh + (size_t)(j + 2320) * 2320);
        const float4* q2 = (const float4*)(W_hh + (size_t)(j + 4640) * 2320);
        float c0 = 0.f, c1 = 0.f, c2 = 0.f;
#pragma unroll 2
        for (int k = lane; k < 580; k += 64) {
          float4 x = s_h4[k];
          c0 += dot4(q0[k], x);
          c1 += dot4(q1[k], x);
          c2 += dot4(q2[k], x);
        }
        a0 = wred(a0); a1 = wred(a1); a2 = wred(a2);
        c0 = wred(c0); c1 = wred(c1); c2 = wred(c2);
        if (lane == 0) {
          float ir = a0 + b_ih[j];
          float iz = a1 + b_ih[j + 2320];
          float ig = a2 + b_ih[j + 4640];
          float hr = c0 + b_hh[j];
          float hz = c1 + b_hh[j + 2320];
          float hg = c2 + b_hh[j + 4640];
          float rr = 1.f / (1.f + expf(-(ir + hr)));
          float zz = 1.f / (1.f + expf(-(iz + hz)));
          float gg = tanhf(ig + rr * hg);
          h_new[j] = (1.f - zz) * gg + zz * s_h[j];
        }
      }
    }
    grid.sync();  // S2: h_new complete

    // ---------- P3: l2 rows, v, c ----------
    {
      const float* h_new = ws + (((t & 1) == 0) ? WS_H1 : WS_H0);
      const float4* hv = (const float4*)h_new;
      for (int i = tid; i < 580; i += 256) s_buf4[i] = hv[i];
      __syncthreads();

      if (gt < 3072) {
        int i = gt / 768, cc = gt - i * 768;
        const float* wcol = W3 + (size_t)(i * 48) * 768 + cc;
        float acc = 0.f;
#pragma unroll 8
        for (int j = 0; j < 48; j++) acc += s_innov[j] * wcol[(size_t)j * 768];
        ws[WS_V + gt] = acc;
      } else if (gt < 3076) {
        int i = gt - 3072;
        float acc = 0.f;
        for (int j = 0; j < 48; j++) acc += s_innov[j] * b3[i * 48 + j];
        ws[WS_C + i] = acc;
      }

      for (int task = wave_g; task < 768; task += NW) {
        const float4* row = (const float4*)(W2 + (size_t)task * 2320);
        float acc = 0.f;
#pragma unroll 2
        for (int k = lane; k < 580; k += 64) acc += dot4(row[k], s_buf4[k]);
        acc = wred(acc);
        if (lane == 0) ws[WS_L2 + task] = fmaxf(acc + b2[task], 0.f);
      }
    }
    grid.sync();  // S3: l2/v/c complete
  }
}

// ======================= fallback multi-launch path =======================
__global__ __launch_bounds__(256) void k_p1a(
    int t, const float* __restrict__ y_seq, const float* __restrict__ x0,
    const float* __restrict__ A, const float* __restrict__ Cm,
    float* __restrict__ out, float* __restrict__ ws)
{
  const int tid = threadIdx.x, lane = tid & 63, wav = tid >> 6;
  __shared__ float s_xpost[4], s_xprior[4], s_innov[48], s_dx[4], s_sc2, s_sc4;
  if (t == 0) {
    if (tid < 4) s_xpost[tid] = x0[tid];
  } else {
    const float4* vv  = (const float4*)(ws + WS_V + wav * 768);
    const float4* l2v = (const float4*)(ws + WS_L2);
    float acc = 0.f;
    for (int k = lane; k < 192; k += 64) acc += dot4(vv[k], l2v[k]);
    acc = wred(acc);
    if (lane == 0) {
      float xn = ws[WS_XPR + wav] + (acc + ws[WS_C + wav]) * 1e-4f;
      s_xpost[wav] = xn;
      out[wav * T_STEPS + (t - 1)] = xn;
    }
  }
  __syncthreads();
  if (t == T_STEPS) return;
  if (tid < 4) {
    float xp = 0.f;
#pragma unroll
    for (int j = 0; j < 4; j++) xp += A[tid * 4 + j] * s_xpost[j];
    s_xprior[tid] = xp;
    ws[WS_XPR + tid] = xp;
  }
  __syncthreads();
  if (tid < 48) {
    float yp = Cm[tid * 5 + 4];
#pragma unroll
    for (int j = 0; j < 4; j++) yp += Cm[tid * 5 + j] * s_xprior[j];
    float inn = y_seq[tid * T_STEPS + t] - yp;
    s_innov[tid] = inn;
    ws[WS_INN + tid] = inn;
  }
  if (tid >= 64 && tid < 68) {
    int i = tid - 64;
    s_dx[i] = s_xpost[i] - s_xprior[i];
  }
  __syncthreads();
  if (tid == 0) {
    float s2 = 0.f;
    for (int r = 0; r < 48; r++) s2 += s_innov[r] * s_innov[r];
    s_sc2 = 1.0f / fmaxf(sqrtf(s2), 1e-12f);
    float s4 = 0.f;
    for (int i = 0; i < 4; i++) s4 += s_dx[i] * s_dx[i];
    s_sc4 = 1.0f / fmaxf(sqrtf(s4), 1e-12f);
  }
  __syncthreads();
  if (tid < 48) ws[WS_KG + tid] = s_innov[tid] * s_sc2;
  else if (tid < 52) ws[WS_KG + tid] = s_dx[tid - 48] * s_sc4;
}

__global__ __launch_bounds__(256) void k_l1(
    const float* __restrict__ W1, const float* __restrict__ b1, float* __restrict__ ws)
{
  __shared__ __align__(16) float s_kg[52];
  const int tid = threadIdx.x, gt = blockIdx.x * 256 + tid;
  if (tid < 52) s_kg[tid] = ws[WS_KG + tid];
  __syncthreads();
  if (gt < 4160) {
    const float4* wr  = (const float4*)(W1 + (size_t)gt * 52);
    const float4* kg4 = (const float4*)s_kg;
    float acc = b1[gt];
#pragma unroll
    for (int k = 0; k < 13; k++) acc += dot4(wr[k], kg4[k]);
    ws[WS_L1 + gt] = fmaxf(acc, 0.f);
  }
}

__global__ __launch_bounds__(256, 2) void k_gru(
    int t, const float* __restrict__ h0, const float* __restrict__ W_ih,
    const float* __restrict__ W_hh, const float* __restrict__ b_ih,
    const float* __restrict__ b_hh, float* __restrict__ ws)
{
  const int tid = threadIdx.x, lane = tid & 63;
  const int wave_g = blockIdx.x * 4 + (tid >> 6);
  const int NW = gridDim.x * 4;
  __shared__ __align__(16) float4 s_l1[1040];
  __shared__ __align__(16) float4 s_h4[580];
  const float* h_old = (t == 0) ? h0 : (ws + (((t & 1) == 0) ? WS_H0 : WS_H1));
  float* h_new = ws + (((t & 1) == 0) ? WS_H1 : WS_H0);
  const float4* l1g = (const float4*)(ws + WS_L1);
  for (int i = tid; i < 1040; i += 256) s_l1[i] = l1g[i];
  const float4* hog = (const float4*)h_old;
  for (int i = tid; i < 580; i += 256) s_h4[i] = hog[i];
  __syncthreads();
  const float* s_h = (const float*)s_h4;

  for (int j = wave_g; j < 2320; j += NW) {
    const float4* r0 = (const float4*)(W_ih + (size_t)j * 4160);
    const float4* r1 = (const float4*)(W_ih + (size_t)(j + 2320) * 4160);
    const float4* r2 = (const float4*)(W_ih + (size_t)(j + 4640) * 4160);
    float a0 = 0.f, a1 = 0.f, a2 = 0.f;
#pragma unroll 2
    for (int k = lane; k < 1040; k += 64) {
      float4 x = s_l1[k];
      a0 += dot4(r0[k], x);
      a1 += dot4(r1[k], x);
      a2 += dot4(r2[k], x);
    }
    const float4* q0 = (const float4*)(W_hh + (size_t)j * 2320);
    const float4* q1 = (const float4*)(W_hh + (size_t)(j + 2320) * 2320);
    const float4* q2 = (const float4*)(W_hh + (size_t)(j + 4640) * 2320);
    float c0 = 0.f, c1 = 0.f, c2 = 0.f;
#pragma unroll 2
    for (int k = lane; k < 580; k += 64) {
      float4 x = s_h4[k];
      c0 += dot4(q0[k], x);
      c1 += dot4(q1[k], x);
      c2 += dot4(q2[k], x);
    }
    a0 = wred(a0); a1 = wred(a1); a2 = wred(a2);
    c0 = wred(c0); c1 = wred(c1); c2 = wred(c2);
    if (lane == 0) {
      float ir = a0 + b_ih[j];
      float iz = a1 + b_ih[j + 2320];
      float ig = a2 + b_ih[j + 4640];
      float hr = c0 + b_hh[j];
      float hz = c1 + b_hh[j + 2320];
      float hg = c2 + b_hh[j + 4640];
      float rr = 1.f / (1.f + expf(-(ir + hr)));
      float zz = 1.f / (1.f + expf(-(iz + hz)));
      float gg = tanhf(ig + rr * hg);
      h_new[j] = (1.f - zz) * gg + zz * s_h[j];
    }
  }
}

__global__ __launch_bounds__(256) void k_p3(
    int t, const float* __restrict__ W2, const float* __restrict__ b2,
    const float* __restrict__ W3, const float* __restrict__ b3, float* __restrict__ ws)
{
  const int tid = threadIdx.x, gt = blockIdx.x * 256 + tid, lane = tid & 63;
  const int wave_g = blockIdx.x * 4 + (tid >> 6);
  const int NW = gridDim.x * 4;
  __shared__ __align__(16) float4 s_hn[580];
  __shared__ float s_innov[48];
  const float* h_new = ws + (((t & 1) == 0) ? WS_H1 : WS_H0);
  const float4* hv = (const float4*)h_new;
  for (int i = tid; i < 580; i += 256) s_hn[i] = hv[i];
  if (tid < 48) s_innov[tid] = ws[WS_INN + tid];
  __syncthreads();

  if (gt < 3072) {
    int i = gt / 768, cc = gt - i * 768;
    const float* wcol = W3 + (size_t)(i * 48) * 768 + cc;
    float acc = 0.f;
#pragma unroll 8
    for (int j = 0; j < 48; j++) acc += s_innov[j] * wcol[(size_t)j * 768];
    ws[WS_V + gt] = acc;
  } else if (gt < 3076) {
    int i = gt - 3072;
    float acc = 0.f;
    for (int j = 0; j < 48; j++) acc += s_innov[j] * b3[i * 48 + j];
    ws[WS_C + i] = acc;
  }

  for (int task = wave_g; task < 768; task += NW) {
    const float4* row = (const float4*)(W2 + (size_t)task * 2320);
    float acc = 0.f;
#pragma unroll 2
    for (int k = lane; k < 580; k += 64) acc += dot4(row[k], s_hn[k]);
    acc = wred(acc);
    if (lane == 0) ws[WS_L2 + task] = fmaxf(acc + b2[task], 0.f);
  }
}

extern "C" void kernel_launch(void* const* d_in, const int* in_sizes, int n_in,
                              void* d_out, int out_size, void* d_ws, size_t ws_size,
                              hipStream_t stream) {
  const float* y_seq = (const float*)d_in[0];
  const float* x0    = (const float*)d_in[1];
  const float* h0    = (const float*)d_in[2];
  const float* A     = (const float*)d_in[3];
  const float* Cm    = (const float*)d_in[4];
  const float* W1    = (const float*)d_in[5];
  const float* b1    = (const float*)d_in[6];
  const float* W_ih  = (const float*)d_in[7];
  const float* W_hh  = (const float*)d_in[8];
  const float* b_ih  = (const float*)d_in[9];
  const float* b_hh  = (const float*)d_in[10];
  const float* W2    = (const float*)d_in[11];
  const float* b2    = (const float*)d_in[12];
  const float* W3    = (const float*)d_in[13];
  const float* b3    = (const float*)d_in[14];
  float* out = (float*)d_out;
  float* ws  = (float*)d_ws;

  void* args[] = { &y_seq, &x0, &h0, &A, &Cm, &W1, &b1, &W_ih, &W_hh,
                   &b_ih, &b_hh, &W2, &b2, &W3, &b3, &out, &ws };
  hipError_t err = hipLaunchCooperativeKernel(
      reinterpret_cast<void*>(knet), dim3(256), dim3(256), args, 0, stream);

  if (err != hipSuccess) {
    // fallback: per-phase kernels; inter-launch ordering = grid-wide sync
    for (int t = 0; t <= T_STEPS; ++t) {
      k_p1a<<<1, 256, 0, stream>>>(t, y_seq, x0, A, Cm, out, ws);
      if (t == T_STEPS) break;
      k_l1<<<17, 256, 0, stream>>>(W1, b1, ws);
      k_gru<<<256, 256, 0, stream>>>(t, h0, W_ih, W_hh, b_ih, b_hh, ws);
      k_p3<<<256, 256, 0, stream>>>(t, W2, b2, W3, b3, ws);
    }
  }
}

// Round 3
// 31035.336 us; speedup vs baseline: 1.1709x; 1.1709x over previous
//
#include <hip/hip_runtime.h>
#include <hip/hip_cooperative_groups.h>

namespace cg = cooperative_groups;

#define T_STEPS 256
// sizes: M=4 N=48 H1=4160 HID=2320 3HID=6960 H2=768 OUT=192 KGIN=52

// workspace layout (float offsets, state area < 16384 floats = 64 KB)
#define WS_L1  0                  // 4160
#define WS_H0  4160               // 2320
#define WS_H1  6480               // 2320
#define WS_L2  8800               // 768
#define WS_V   9568               // 4*768
#define WS_C   12640              // 4
#define WS_XPO 12644
#define WS_XPR 12648
#define WS_INN 12656
#define WS_KG  12704

// bf16 weight area (byte offsets into ws)
#define BW_BASE   65536
#define N_IH      28953600        // 6960*4160
#define N_HH      16147200        // 6960*2320
#define N_W2      1781760         // 768*2320
#define BW_IH_OFF (BW_BASE)
#define BW_HH_OFF (BW_IH_OFF + N_IH * 2)
#define BW_W2_OFF (BW_HH_OFF + N_HH * 2)
#define BW_END    (BW_W2_OFF + (size_t)N_W2 * 2)

__device__ __forceinline__ float wred(float v) {
#pragma unroll
  for (int m = 32; m; m >>= 1) v += __shfl_xor(v, m, 64);
  return v;
}
__device__ __forceinline__ float dot4(float4 a, float4 b) {
  return a.x * b.x + a.y * b.y + a.z * b.z + a.w * b.w;
}
__device__ __forceinline__ float blo(unsigned u) {
  unsigned t = u << 16; return __builtin_bit_cast(float, t);
}
__device__ __forceinline__ float bhi(unsigned u) {
  unsigned t = u & 0xFFFF0000u; return __builtin_bit_cast(float, t);
}
// 8-elem bf16 dot against two fp32 float4s
__device__ __forceinline__ float dot8(uint4 w, float4 x0, float4 x1) {
  return blo(w.x) * x0.x + bhi(w.x) * x0.y + blo(w.y) * x0.z + bhi(w.y) * x0.w +
         blo(w.z) * x1.x + bhi(w.z) * x1.y + blo(w.w) * x1.z + bhi(w.w) * x1.w;
}
__device__ __forceinline__ unsigned short f2bf(float f) {  // RNE
  unsigned u = __builtin_bit_cast(unsigned, f);
  unsigned r = u + 0x7FFF + ((u >> 16) & 1);
  return (unsigned short)(r >> 16);
}

// ---------------- fp32 -> bf16 conversion (vector) ----------------
__global__ __launch_bounds__(256) void k_cvt(const float4* __restrict__ src,
                                             ushort4* __restrict__ dst, int n4) {
  int i = blockIdx.x * 256 + threadIdx.x, st = gridDim.x * 256;
  for (; i < n4; i += st) {
    float4 v = src[i];
    ushort4 o;
    o.x = f2bf(v.x); o.y = f2bf(v.y); o.z = f2bf(v.z); o.w = f2bf(v.w);
    dst[i] = o;
  }
}

// ================= cooperative bf16-weight kernel =================
__global__ __launch_bounds__(256, 3) void knet_bf(
    const float* __restrict__ y_seq, const float* __restrict__ x0,
    const float* __restrict__ h0, const float* __restrict__ A,
    const float* __restrict__ Cm, const float* __restrict__ W1,
    const float* __restrict__ b1, const unsigned short* __restrict__ bwih,
    const unsigned short* __restrict__ bwhh, const float* __restrict__ b_ih,
    const float* __restrict__ b_hh, const unsigned short* __restrict__ bw2,
    const float* __restrict__ b2, const float* __restrict__ W3,
    const float* __restrict__ b3, float* __restrict__ out,
    float* __restrict__ ws)
{
  cg::grid_group grid = cg::this_grid();
  const int tid    = threadIdx.x;
  const int lane   = tid & 63;
  const int wav    = tid >> 6;
  const int bid    = blockIdx.x;
  const int gt     = bid * 256 + tid;
  const int wave_g = bid * 4 + wav;
  const int NW     = gridDim.x * 4;

  __shared__ __align__(16) float4 s_buf4[1040];   // l1 (P2) / h_new (P3)
  __shared__ __align__(16) float4 s_h4[580];      // h_old (P2)
  __shared__ __align__(16) float s_kgin[52];
  __shared__ float s_innov[48];
  __shared__ float s_xpost[4], s_xprior[4], s_dx[4];
  __shared__ float s_sc2, s_sc4;

  for (int t = 0; t <= T_STEPS; ++t) {
    // ---------- P1a: x_post ----------
    if (t == 0) {
      if (tid < 4) s_xpost[tid] = x0[tid];
    } else {
      const float4* vv  = (const float4*)(ws + WS_V + wav * 768);
      const float4* l2v = (const float4*)(ws + WS_L2);
      float acc = 0.f;
#pragma unroll 3
      for (int k = lane; k < 192; k += 64) acc += dot4(vv[k], l2v[k]);
      acc = wred(acc);
      if (lane == 0)
        s_xpost[wav] = s_xprior[wav] + (acc + ws[WS_C + wav]) * 1e-4f;
    }
    __syncthreads();
    if (bid == 0 && t > 0 && tid < 4) out[tid * T_STEPS + (t - 1)] = s_xpost[tid];
    if (t == T_STEPS) return;

    // ---------- P1b: x_prior, innov, kg_in ----------
    if (tid < 4) {
      float xp = 0.f;
#pragma unroll
      for (int j = 0; j < 4; j++) xp += A[tid * 4 + j] * s_xpost[j];
      s_xprior[tid] = xp;
    }
    __syncthreads();
    if (tid < 48) {
      float yp = Cm[tid * 5 + 4];
#pragma unroll
      for (int j = 0; j < 4; j++) yp += Cm[tid * 5 + j] * s_xprior[j];
      s_innov[tid] = y_seq[tid * T_STEPS + t] - yp;
    }
    if (tid >= 64 && tid < 68) {
      int i = tid - 64;
      s_dx[i] = s_xpost[i] - s_xprior[i];
    }
    __syncthreads();
    if (tid == 0) {
      float s2 = 0.f;
      for (int r = 0; r < 48; r++) s2 += s_innov[r] * s_innov[r];
      s_sc2 = 1.0f / fmaxf(sqrtf(s2), 1e-12f);
      float s4 = 0.f;
      for (int i = 0; i < 4; i++) s4 += s_dx[i] * s_dx[i];
      s_sc4 = 1.0f / fmaxf(sqrtf(s4), 1e-12f);
    }
    __syncthreads();
    if (tid < 48) s_kgin[tid] = s_innov[tid] * s_sc2;
    else if (tid < 52) s_kgin[tid] = s_dx[tid - 48] * s_sc4;
    __syncthreads();

    // ---------- P1c: l1 ----------
    if (gt < 4160) {
      const float4* wr  = (const float4*)(W1 + (size_t)gt * 52);
      const float4* kg4 = (const float4*)s_kgin;
      float acc = b1[gt];
#pragma unroll
      for (int k = 0; k < 13; k++) acc += dot4(wr[k], kg4[k]);
      ws[WS_L1 + gt] = fmaxf(acc, 0.f);
    }
    grid.sync();  // S1

    // ---------- P2: GRU ----------
    {
      const float* h_old = (t == 0) ? h0 : (ws + (((t & 1) == 0) ? WS_H0 : WS_H1));
      float* h_new = ws + (((t & 1) == 0) ? WS_H1 : WS_H0);
      const float4* l1g = (const float4*)(ws + WS_L1);
      for (int i = tid; i < 1040; i += 256) s_buf4[i] = l1g[i];
      const float4* hog = (const float4*)h_old;
      for (int i = tid; i < 580; i += 256) s_h4[i] = hog[i];
      __syncthreads();
      const float* s_h = (const float*)s_h4;

      for (int j = wave_g; j < 2320; j += NW) {
        const uint4* r0 = (const uint4*)(bwih + (size_t)j * 4160);
        const uint4* r1 = (const uint4*)(bwih + (size_t)(j + 2320) * 4160);
        const uint4* r2 = (const uint4*)(bwih + (size_t)(j + 4640) * 4160);
        float a0 = 0.f, a1 = 0.f, a2 = 0.f;
#pragma unroll 4
        for (int k = lane; k < 520; k += 64) {   // 520 uint4 = 4160 bf16
          float4 x0v = s_buf4[2 * k], x1v = s_buf4[2 * k + 1];
          a0 += dot8(r0[k], x0v, x1v);
          a1 += dot8(r1[k], x0v, x1v);
          a2 += dot8(r2[k], x0v, x1v);
        }
        const uint4* q0 = (const uint4*)(bwhh + (size_t)j * 2320);
        const uint4* q1 = (const uint4*)(bwhh + (size_t)(j + 2320) * 2320);
        const uint4* q2 = (const uint4*)(bwhh + (size_t)(j + 4640) * 2320);
        float c0 = 0.f, c1 = 0.f, c2 = 0.f;
#pragma unroll 4
        for (int k = lane; k < 290; k += 64) {   // 290 uint4 = 2320 bf16
          float4 x0v = s_h4[2 * k], x1v = s_h4[2 * k + 1];
          c0 += dot8(q0[k], x0v, x1v);
          c1 += dot8(q1[k], x0v, x1v);
          c2 += dot8(q2[k], x0v, x1v);
        }
        a0 = wred(a0); a1 = wred(a1); a2 = wred(a2);
        c0 = wred(c0); c1 = wred(c1); c2 = wred(c2);
        if (lane == 0) {
          float ir = a0 + b_ih[j];
          float iz = a1 + b_ih[j + 2320];
          float ig = a2 + b_ih[j + 4640];
          float hr = c0 + b_hh[j];
          float hz = c1 + b_hh[j + 2320];
          float hg = c2 + b_hh[j + 4640];
          float rr = 1.f / (1.f + expf(-(ir + hr)));
          float zz = 1.f / (1.f + expf(-(iz + hz)));
          float gg = tanhf(ig + rr * hg);
          h_new[j] = (1.f - zz) * gg + zz * s_h[j];
        }
      }
    }
    grid.sync();  // S2

    // ---------- P3: l2, v, c ----------
    {
      const float* h_new = ws + (((t & 1) == 0) ? WS_H1 : WS_H0);
      const float4* hv = (const float4*)h_new;
      for (int i = tid; i < 580; i += 256) s_buf4[i] = hv[i];
      __syncthreads();

      if (gt < 3072) {
        int i = gt / 768, cc = gt - i * 768;
        const float* wcol = W3 + (size_t)(i * 48) * 768 + cc;
        float acc = 0.f;
#pragma unroll 8
        for (int j = 0; j < 48; j++) acc += s_innov[j] * wcol[(size_t)j * 768];
        ws[WS_V + gt] = acc;
      } else if (gt < 3076) {
        int i = gt - 3072;
        float acc = 0.f;
        for (int j = 0; j < 48; j++) acc += s_innov[j] * b3[i * 48 + j];
        ws[WS_C + i] = acc;
      }

      for (int task = wave_g; task < 768; task += NW) {
        const uint4* row = (const uint4*)(bw2 + (size_t)task * 2320);
        float acc = 0.f;
#pragma unroll 4
        for (int k = lane; k < 290; k += 64) {
          float4 x0v = s_buf4[2 * k], x1v = s_buf4[2 * k + 1];
          acc += dot8(row[k], x0v, x1v);
        }
        acc = wred(acc);
        if (lane == 0) ws[WS_L2 + task] = fmaxf(acc + b2[task], 0.f);
      }
    }
    grid.sync();  // S3
  }
}

// ================= cooperative fp32 kernel (fallback 1) =================
__global__ __launch_bounds__(256, 2) void knet(
    const float* __restrict__ y_seq, const float* __restrict__ x0,
    const float* __restrict__ h0, const float* __restrict__ A,
    const float* __restrict__ Cm, const float* __restrict__ W1,
    const float* __restrict__ b1, const float* __restrict__ W_ih,
    const float* __restrict__ W_hh, const float* __restrict__ b_ih,
    const float* __restrict__ b_hh, const float* __restrict__ W2,
    const float* __restrict__ b2, const float* __restrict__ W3,
    const float* __restrict__ b3, float* __restrict__ out,
    float* __restrict__ ws)
{
  cg::grid_group grid = cg::this_grid();
  const int tid = threadIdx.x, lane = tid & 63, wav = tid >> 6, bid = blockIdx.x;
  const int gt = bid * 256 + tid, wave_g = bid * 4 + wav, NW = gridDim.x * 4;

  __shared__ __align__(16) float4 s_buf4[1040];
  __shared__ __align__(16) float4 s_h4[580];
  __shared__ __align__(16) float s_kgin[52];
  __shared__ float s_innov[48];
  __shared__ float s_xpost[4], s_xprior[4], s_dx[4];
  __shared__ float s_sc2, s_sc4;

  for (int t = 0; t <= T_STEPS; ++t) {
    if (t == 0) {
      if (tid < 4) s_xpost[tid] = x0[tid];
    } else {
      const float4* vv  = (const float4*)(ws + WS_V + wav * 768);
      const float4* l2v = (const float4*)(ws + WS_L2);
      float acc = 0.f;
      for (int k = lane; k < 192; k += 64) acc += dot4(vv[k], l2v[k]);
      acc = wred(acc);
      if (lane == 0)
        s_xpost[wav] = s_xprior[wav] + (acc + ws[WS_C + wav]) * 1e-4f;
    }
    __syncthreads();
    if (bid == 0 && t > 0 && tid < 4) out[tid * T_STEPS + (t - 1)] = s_xpost[tid];
    if (t == T_STEPS) return;

    if (tid < 4) {
      float xp = 0.f;
#pragma unroll
      for (int j = 0; j < 4; j++) xp += A[tid * 4 + j] * s_xpost[j];
      s_xprior[tid] = xp;
    }
    __syncthreads();
    if (tid < 48) {
      float yp = Cm[tid * 5 + 4];
#pragma unroll
      for (int j = 0; j < 4; j++) yp += Cm[tid * 5 + j] * s_xprior[j];
      s_innov[tid] = y_seq[tid * T_STEPS + t] - yp;
    }
    if (tid >= 64 && tid < 68) {
      int i = tid - 64;
      s_dx[i] = s_xpost[i] - s_xprior[i];
    }
    __syncthreads();
    if (tid == 0) {
      float s2 = 0.f;
      for (int r = 0; r < 48; r++) s2 += s_innov[r] * s_innov[r];
      s_sc2 = 1.0f / fmaxf(sqrtf(s2), 1e-12f);
      float s4 = 0.f;
      for (int i = 0; i < 4; i++) s4 += s_dx[i] * s_dx[i];
      s_sc4 = 1.0f / fmaxf(sqrtf(s4), 1e-12f);
    }
    __syncthreads();
    if (tid < 48) s_kgin[tid] = s_innov[tid] * s_sc2;
    else if (tid < 52) s_kgin[tid] = s_dx[tid - 48] * s_sc4;
    __syncthreads();

    if (gt < 4160) {
      const float4* wr  = (const float4*)(W1 + (size_t)gt * 52);
      const float4* kg4 = (const float4*)s_kgin;
      float acc = b1[gt];
#pragma unroll
      for (int k = 0; k < 13; k++) acc += dot4(wr[k], kg4[k]);
      ws[WS_L1 + gt] = fmaxf(acc, 0.f);
    }
    grid.sync();

    {
      const float* h_old = (t == 0) ? h0 : (ws + (((t & 1) == 0) ? WS_H0 : WS_H1));
      float* h_new = ws + (((t & 1) == 0) ? WS_H1 : WS_H0);
      const float4* l1g = (const float4*)(ws + WS_L1);
      for (int i = tid; i < 1040; i += 256) s_buf4[i] = l1g[i];
      const float4* hog = (const float4*)h_old;
      for (int i = tid; i < 580; i += 256) s_h4[i] = hog[i];
      __syncthreads();
      const float* s_h = (const float*)s_h4;

      for (int j = wave_g; j < 2320; j += NW) {
        const float4* r0 = (const float4*)(W_ih + (size_t)j * 4160);
        const float4* r1 = (const float4*)(W_ih + (size_t)(j + 2320) * 4160);
        const float4* r2 = (const float4*)(W_ih + (size_t)(j + 4640) * 4160);
        float a0 = 0.f, a1 = 0.f, a2 = 0.f;
#pragma unroll 4
        for (int k = lane; k < 1040; k += 64) {
          float4 x = s_buf4[k];
          a0 += dot4(r0[k], x); a1 += dot4(r1[k], x); a2 += dot4(r2[k], x);
        }
        const float4* q0 = (const float4*)(W_hh + (size_t)j * 2320);
        const float4* q1 = (const float4*)(W_hh + (size_t)(j + 2320) * 2320);
        const float4* q2 = (const float4*)(W_hh + (size_t)(j + 4640) * 2320);
        float c0 = 0.f, c1 = 0.f, c2 = 0.f;
#pragma unroll 4
        for (int k = lane; k < 580; k += 64) {
          float4 x = s_h4[k];
          c0 += dot4(q0[k], x); c1 += dot4(q1[k], x); c2 += dot4(q2[k], x);
        }
        a0 = wred(a0); a1 = wred(a1); a2 = wred(a2);
        c0 = wred(c0); c1 = wred(c1); c2 = wred(c2);
        if (lane == 0) {
          float ir = a0 + b_ih[j], iz = a1 + b_ih[j + 2320], ig = a2 + b_ih[j + 4640];
          float hr = c0 + b_hh[j], hz = c1 + b_hh[j + 2320], hg = c2 + b_hh[j + 4640];
          float rr = 1.f / (1.f + expf(-(ir + hr)));
          float zz = 1.f / (1.f + expf(-(iz + hz)));
          float gg = tanhf(ig + rr * hg);
          h_new[j] = (1.f - zz) * gg + zz * s_h[j];
        }
      }
    }
    grid.sync();

    {
      const float* h_new = ws + (((t & 1) == 0) ? WS_H1 : WS_H0);
      const float4* hv = (const float4*)h_new;
      for (int i = tid; i < 580; i += 256) s_buf4[i] = hv[i];
      __syncthreads();

      if (gt < 3072) {
        int i = gt / 768, cc = gt - i * 768;
        const float* wcol = W3 + (size_t)(i * 48) * 768 + cc;
        float acc = 0.f;
#pragma unroll 8
        for (int j = 0; j < 48; j++) acc += s_innov[j] * wcol[(size_t)j * 768];
        ws[WS_V + gt] = acc;
      } else if (gt < 3076) {
        int i = gt - 3072;
        float acc = 0.f;
        for (int j = 0; j < 48; j++) acc += s_innov[j] * b3[i * 48 + j];
        ws[WS_C + i] = acc;
      }

      for (int task = wave_g; task < 768; task += NW) {
        const float4* row = (const float4*)(W2 + (size_t)task * 2320);
        float acc = 0.f;
#pragma unroll 4
        for (int k = lane; k < 580; k += 64) acc += dot4(row[k], s_buf4[k]);
        acc = wred(acc);
        if (lane == 0) ws[WS_L2 + task] = fmaxf(acc + b2[task], 0.f);
      }
    }
    grid.sync();
  }
}

// ================= multi-launch fp32 path (fallback 2) =================
__global__ __launch_bounds__(256) void k_p1a(
    int t, const float* __restrict__ y_seq, const float* __restrict__ x0,
    const float* __restrict__ A, const float* __restrict__ Cm,
    float* __restrict__ out, float* __restrict__ ws)
{
  const int tid = threadIdx.x, lane = tid & 63, wav = tid >> 6;
  __shared__ float s_xpost[4], s_xprior[4], s_innov[48], s_dx[4], s_sc2, s_sc4;
  if (t == 0) {
    if (tid < 4) s_xpost[tid] = x0[tid];
  } else {
    const float4* vv  = (const float4*)(ws + WS_V + wav * 768);
    const float4* l2v = (const float4*)(ws + WS_L2);
    float acc = 0.f;
    for (int k = lane; k < 192; k += 64) acc += dot4(vv[k], l2v[k]);
    acc = wred(acc);
    if (lane == 0) {
      float xn = ws[WS_XPR + wav] + (acc + ws[WS_C + wav]) * 1e-4f;
      s_xpost[wav] = xn;
      out[wav * T_STEPS + (t - 1)] = xn;
    }
  }
  __syncthreads();
  if (t == T_STEPS) return;
  if (tid < 4) {
    float xp = 0.f;
#pragma unroll
    for (int j = 0; j < 4; j++) xp += A[tid * 4 + j] * s_xpost[j];
    s_xprior[tid] = xp;
    ws[WS_XPR + tid] = xp;
  }
  __syncthreads();
  if (tid < 48) {
    float yp = Cm[tid * 5 + 4];
#pragma unroll
    for (int j = 0; j < 4; j++) yp += Cm[tid * 5 + j] * s_xprior[j];
    float inn = y_seq[tid * T_STEPS + t] - yp;
    s_innov[tid] = inn;
    ws[WS_INN + tid] = inn;
  }
  if (tid >= 64 && tid < 68) {
    int i = tid - 64;
    s_dx[i] = s_xpost[i] - s_xprior[i];
  }
  __syncthreads();
  if (tid == 0) {
    float s2 = 0.f;
    for (int r = 0; r < 48; r++) s2 += s_innov[r] * s_innov[r];
    s_sc2 = 1.0f / fmaxf(sqrtf(s2), 1e-12f);
    float s4 = 0.f;
    for (int i = 0; i < 4; i++) s4 += s_dx[i] * s_dx[i];
    s_sc4 = 1.0f / fmaxf(sqrtf(s4), 1e-12f);
  }
  __syncthreads();
  if (tid < 48) ws[WS_KG + tid] = s_innov[tid] * s_sc2;
  else if (tid < 52) ws[WS_KG + tid] = s_dx[tid - 48] * s_sc4;
}

__global__ __launch_bounds__(256) void k_l1(
    const float* __restrict__ W1, const float* __restrict__ b1, float* __restrict__ ws)
{
  __shared__ __align__(16) float s_kg[52];
  const int tid = threadIdx.x, gt = blockIdx.x * 256 + tid;
  if (tid < 52) s_kg[tid] = ws[WS_KG + tid];
  __syncthreads();
  if (gt < 4160) {
    const float4* wr  = (const float4*)(W1 + (size_t)gt * 52);
    const float4* kg4 = (const float4*)s_kg;
    float acc = b1[gt];
#pragma unroll
    for (int k = 0; k < 13; k++) acc += dot4(wr[k], kg4[k]);
    ws[WS_L1 + gt] = fmaxf(acc, 0.f);
  }
}

__global__ __launch_bounds__(256, 2) void k_gru(
    int t, const float* __restrict__ h0, const float* __restrict__ W_ih,
    const float* __restrict__ W_hh, const float* __restrict__ b_ih,
    const float* __restrict__ b_hh, float* __restrict__ ws)
{
  const int tid = threadIdx.x, lane = tid & 63;
  const int wave_g = blockIdx.x * 4 + (tid >> 6);
  const int NW = gridDim.x * 4;
  __shared__ __align__(16) float4 s_l1[1040];
  __shared__ __align__(16) float4 s_h4[580];
  const float* h_old = (t == 0) ? h0 : (ws + (((t & 1) == 0) ? WS_H0 : WS_H1));
  float* h_new = ws + (((t & 1) == 0) ? WS_H1 : WS_H0);
  const float4* l1g = (const float4*)(ws + WS_L1);
  for (int i = tid; i < 1040; i += 256) s_l1[i] = l1g[i];
  const float4* hog = (const float4*)h_old;
  for (int i = tid; i < 580; i += 256) s_h4[i] = hog[i];
  __syncthreads();
  const float* s_h = (const float*)s_h4;

  for (int j = wave_g; j < 2320; j += NW) {
    const float4* r0 = (const float4*)(W_ih + (size_t)j * 4160);
    const float4* r1 = (const float4*)(W_ih + (size_t)(j + 2320) * 4160);
    const float4* r2 = (const float4*)(W_ih + (size_t)(j + 4640) * 4160);
    float a0 = 0.f, a1 = 0.f, a2 = 0.f;
#pragma unroll 2
    for (int k = lane; k < 1040; k += 64) {
      float4 x = s_l1[k];
      a0 += dot4(r0[k], x); a1 += dot4(r1[k], x); a2 += dot4(r2[k], x);
    }
    const float4* q0 = (const float4*)(W_hh + (size_t)j * 2320);
    const float4* q1 = (const float4*)(W_hh + (size_t)(j + 2320) * 2320);
    const float4* q2 = (const float4*)(W_hh + (size_t)(j + 4640) * 2320);
    float c0 = 0.f, c1 = 0.f, c2 = 0.f;
#pragma unroll 2
    for (int k = lane; k < 580; k += 64) {
      float4 x = s_h4[k];
      c0 += dot4(q0[k], x); c1 += dot4(q1[k], x); c2 += dot4(q2[k], x);
    }
    a0 = wred(a0); a1 = wred(a1); a2 = wred(a2);
    c0 = wred(c0); c1 = wred(c1); c2 = wred(c2);
    if (lane == 0) {
      float ir = a0 + b_ih[j], iz = a1 + b_ih[j + 2320], ig = a2 + b_ih[j + 4640];
      float hr = c0 + b_hh[j], hz = c1 + b_hh[j + 2320], hg = c2 + b_hh[j + 4640];
      float rr = 1.f / (1.f + expf(-(ir + hr)));
      float zz = 1.f / (1.f + expf(-(iz + hz)));
      float gg = tanhf(ig + rr * hg);
      h_new[j] = (1.f - zz) * gg + zz * s_h[j];
    }
  }
}

__global__ __launch_bounds__(256) void k_p3(
    int t, const float* __restrict__ W2, const float* __restrict__ b2,
    const float* __restrict__ W3, const float* __restrict__ b3, float* __restrict__ ws)
{
  const int tid = threadIdx.x, gt = blockIdx.x * 256 + tid, lane = tid & 63;
  const int wave_g = blockIdx.x * 4 + (tid >> 6);
  const int NW = gridDim.x * 4;
  __shared__ __align__(16) float4 s_hn[580];
  __shared__ float s_innov[48];
  const float* h_new = ws + (((t & 1) == 0) ? WS_H1 : WS_H0);
  const float4* hv = (const float4*)h_new;
  for (int i = tid; i < 580; i += 256) s_hn[i] = hv[i];
  if (tid < 48) s_innov[tid] = ws[WS_INN + tid];
  __syncthreads();

  if (gt < 3072) {
    int i = gt / 768, cc = gt - i * 768;
    const float* wcol = W3 + (size_t)(i * 48) * 768 + cc;
    float acc = 0.f;
#pragma unroll 8
    for (int j = 0; j < 48; j++) acc += s_innov[j] * wcol[(size_t)j * 768];
    ws[WS_V + gt] = acc;
  } else if (gt < 3076) {
    int i = gt - 3072;
    float acc = 0.f;
    for (int j = 0; j < 48; j++) acc += s_innov[j] * b3[i * 48 + j];
    ws[WS_C + i] = acc;
  }

  for (int task = wave_g; task < 768; task += NW) {
    const float4* row = (const float4*)(W2 + (size_t)task * 2320);
    float acc = 0.f;
#pragma unroll 2
    for (int k = lane; k < 580; k += 64) acc += dot4(row[k], s_hn[k]);
    acc = wred(acc);
    if (lane == 0) ws[WS_L2 + task] = fmaxf(acc + b2[task], 0.f);
  }
}

extern "C" void kernel_launch(void* const* d_in, const int* in_sizes, int n_in,
                              void* d_out, int out_size, void* d_ws, size_t ws_size,
                              hipStream_t stream) {
  const float* y_seq = (const float*)d_in[0];
  const float* x0    = (const float*)d_in[1];
  const float* h0    = (const float*)d_in[2];
  const float* A     = (const float*)d_in[3];
  const float* Cm    = (const float*)d_in[4];
  const float* W1    = (const float*)d_in[5];
  const float* b1    = (const float*)d_in[6];
  const float* W_ih  = (const float*)d_in[7];
  const float* W_hh  = (const float*)d_in[8];
  const float* b_ih  = (const float*)d_in[9];
  const float* b_hh  = (const float*)d_in[10];
  const float* W2    = (const float*)d_in[11];
  const float* b2    = (const float*)d_in[12];
  const float* W3    = (const float*)d_in[13];
  const float* b3    = (const float*)d_in[14];
  float* out = (float*)d_out;
  float* ws  = (float*)d_ws;

  if (ws_size >= BW_END + 1024) {
    char* wsb = (char*)d_ws;
    unsigned short* bwih = (unsigned short*)(wsb + BW_IH_OFF);
    unsigned short* bwhh = (unsigned short*)(wsb + BW_HH_OFF);
    unsigned short* bw2  = (unsigned short*)(wsb + BW_W2_OFF);

    k_cvt<<<1024, 256, 0, stream>>>((const float4*)W_ih, (ushort4*)bwih, N_IH / 4);
    k_cvt<<<1024, 256, 0, stream>>>((const float4*)W_hh, (ushort4*)bwhh, N_HH / 4);
    k_cvt<<<512, 256, 0, stream>>>((const float4*)W2, (ushort4*)bw2, N_W2 / 4);

    int nb = 0;
    hipError_t oe = hipOccupancyMaxActiveBlocksPerMultiprocessor(
        &nb, (const void*)knet_bf, 256, 0);
    int bpc = (oe == hipSuccess && nb >= 1) ? (nb > 3 ? 3 : nb) : 1;

    void* args[] = { &y_seq, &x0, &h0, &A, &Cm, &W1, &b1, &bwih, &bwhh,
                     &b_ih, &b_hh, &bw2, &b2, &W3, &b3, &out, &ws };
    hipError_t err = hipLaunchCooperativeKernel(
        reinterpret_cast<void*>(knet_bf), dim3(256 * bpc), dim3(256), args, 0, stream);
    if (err == hipSuccess) return;
  }

  {
    int nb = 0;
    hipError_t oe = hipOccupancyMaxActiveBlocksPerMultiprocessor(
        &nb, (const void*)knet, 256, 0);
    int bpc = (oe == hipSuccess && nb >= 1) ? (nb > 3 ? 3 : nb) : 1;
    void* args[] = { &y_seq, &x0, &h0, &A, &Cm, &W1, &b1, &W_ih, &W_hh,
                     &b_ih, &b_hh, &W2, &b2, &W3, &b3, &out, &ws };
    hipError_t err = hipLaunchCooperativeKernel(
        reinterpret_cast<void*>(knet), dim3(256 * bpc), dim3(256), args, 0, stream);
    if (err == hipSuccess) return;
  }

  for (int t = 0; t <= T_STEPS; ++t) {
    k_p1a<<<1, 256, 0, stream>>>(t, y_seq, x0, A, Cm, out, ws);
    if (t == T_STEPS) break;
    k_l1<<<17, 256, 0, stream>>>(W1, b1, ws);
    k_gru<<<256, 256, 0, stream>>>(t, h0, W_ih, W_hh, b_ih, b_hh, ws);
    k_p3<<<256, 256, 0, stream>>>(t, W2, b2, W3, b3, ws);
  }
}